// Round 2
// baseline (979.655 us; speedup 1.0000x reference)
//
#include <hip/hip_runtime.h>
#include <hip/hip_bf16.h>

#define H 1024
#define SEQ 4096
#define BQ 64   // Kq
#define NB 16   // batch

typedef float f32x4 __attribute__((ext_vector_type(4)));
typedef __bf16 bf16x8 __attribute__((ext_vector_type(8)));

__device__ __forceinline__ void split_bf16(const float* x, bf16x8& hi, bf16x8& lo)
{
    #pragma unroll
    for (int i = 0; i < 8; ++i) {
        float v = x[i];
        __bf16 h = (__bf16)v;
        hi[i] = h;
        lo[i] = (__bf16)(v - (float)h);
    }
}

// ---------------------------------------------------------------------------
// GEMM: C[1024x1024] = (sum_p A_p) @ B * scale + bias   (f32 VALU, small)
// BNK true:  B[n*H+k] (X @ W^T). BNK false: B[k*H+n] (X @ W).
// ---------------------------------------------------------------------------
template<bool BNK>
__global__ __launch_bounds__(256)
void gemm_sum(const float* __restrict__ A, int npart, size_t pstride,
              const float* __restrict__ Bm, const float* __restrict__ bias,
              float* __restrict__ C, float scale)
{
    __shared__ float As[32][68];
    __shared__ float Bs[32][68];
    const int m0 = blockIdx.x * 64;
    const int n0 = blockIdx.y * 64;
    const int t  = threadIdx.x;
    const int tn = t & 15;
    const int tm = t >> 4;
    float acc[4][4] = {};

    for (int k0 = 0; k0 < H; k0 += 32) {
        {   // stage A (summed over partials): As[k][m]
            int kk = t & 31;
            int mb = (t >> 5) * 8;
            #pragma unroll
            for (int r = 0; r < 8; ++r) {
                size_t idx = (size_t)(m0 + mb + r) * H + k0 + kk;
                float v = A[idx];
                for (int p = 1; p < npart; ++p) v += A[(size_t)p * pstride + idx];
                As[kk][mb + r] = v;
            }
        }
        if (BNK) {
            int kk = t & 31;
            int nb = (t >> 5) * 8;
            #pragma unroll
            for (int r = 0; r < 8; ++r)
                Bs[kk][nb + r] = Bm[(size_t)(n0 + nb + r) * H + k0 + kk];
        } else {
            int n  = t & 63;
            int kb = (t >> 6) * 8;
            #pragma unroll
            for (int r = 0; r < 8; ++r)
                Bs[kb + r][n] = Bm[(size_t)(k0 + kb + r) * H + n0 + n];
        }
        __syncthreads();
        #pragma unroll 8
        for (int kk = 0; kk < 32; ++kk) {
            float4 a4 = *reinterpret_cast<const float4*>(&As[kk][tm * 4]);
            float4 b4 = *reinterpret_cast<const float4*>(&Bs[kk][tn * 4]);
            float av[4] = {a4.x, a4.y, a4.z, a4.w};
            float bv2[4] = {b4.x, b4.y, b4.z, b4.w};
            #pragma unroll
            for (int i = 0; i < 4; ++i)
                #pragma unroll
                for (int j = 0; j < 4; ++j)
                    acc[i][j] += av[i] * bv2[j];
        }
        __syncthreads();
    }

    #pragma unroll
    for (int i = 0; i < 4; ++i) {
        int m = m0 + tm * 4 + i;
        float4 o;
        float* po = &o.x;
        #pragma unroll
        for (int j = 0; j < 4; ++j) {
            float v = acc[i][j] * scale;
            if (bias) v += bias[n0 + tn * 4 + j];
            po[j] = v;
        }
        *reinterpret_cast<float4*>(&C[(size_t)m * H + n0 + tn * 4]) = o;
    }
}

// ---------------------------------------------------------------------------
// c[b,qi] = scale * dot(q[b,qi,:], bk)
// ---------------------------------------------------------------------------
__global__ __launch_bounds__(256)
void cvec_kernel(const float* __restrict__ q, const float* __restrict__ bk,
                 float* __restrict__ cvec, float scale)
{
    int r = blockIdx.x * 4 + (threadIdx.x >> 6);
    int l = threadIdx.x & 63;
    float s = 0.f;
    #pragma unroll
    for (int i = 0; i < 16; ++i)
        s += q[(size_t)r * H + l + 64 * i] * bk[l + 64 * i];
    #pragma unroll
    for (int off = 32; off; off >>= 1)
        s += __shfl_down(s, off);
    if (l == 0) cvec[r] = s * scale;
}

// ---------------------------------------------------------------------------
// scores[b,s,qi] = sum_h keys[b,s,h]*N[b,qi,h] + c[b,qi]  (MFMA, hi/lo split)
// block: 64 s x 64 qi, wave w handles 16 s; grid (SEQ/64, NB)
// ---------------------------------------------------------------------------
__global__ __launch_bounds__(256)
void scores_mfma(const float* __restrict__ keys, const float* __restrict__ Nw,
                 const float* __restrict__ cvec, float* __restrict__ scores)
{
    const int b   = blockIdx.y;
    const int s0  = blockIdx.x * 64;
    const int w   = threadIdx.x >> 6;
    const int l   = threadIdx.x & 63;
    const int row = l & 15;
    const int kg  = l >> 4;

    const float* ka = keys + ((size_t)b * SEQ + s0 + w * 16 + row) * H + kg * 8;
    const float* nb = Nw + (size_t)b * BQ * H + (size_t)row * H + kg * 8;

    f32x4 acc[4] = {};
    for (int k0 = 0; k0 < H; k0 += 32) {
        float a8[8];
        *reinterpret_cast<float4*>(&a8[0]) = *reinterpret_cast<const float4*>(ka + k0);
        *reinterpret_cast<float4*>(&a8[4]) = *reinterpret_cast<const float4*>(ka + k0 + 4);
        bf16x8 ahi, alo;
        split_bf16(a8, ahi, alo);
        #pragma unroll
        for (int j = 0; j < 4; ++j) {
            float b8[8];
            const float* bp = nb + (size_t)j * 16 * H + k0;
            *reinterpret_cast<float4*>(&b8[0]) = *reinterpret_cast<const float4*>(bp);
            *reinterpret_cast<float4*>(&b8[4]) = *reinterpret_cast<const float4*>(bp + 4);
            bf16x8 bhi, blo;
            split_bf16(b8, bhi, blo);
            acc[j] = __builtin_amdgcn_mfma_f32_16x16x32_bf16(ahi, bhi, acc[j], 0, 0, 0);
            acc[j] = __builtin_amdgcn_mfma_f32_16x16x32_bf16(ahi, blo, acc[j], 0, 0, 0);
            acc[j] = __builtin_amdgcn_mfma_f32_16x16x32_bf16(alo, bhi, acc[j], 0, 0, 0);
        }
    }
    // D: col(lane&15)=qi within n-tile, row((lane>>4)*4+r)=s within m-tile
    #pragma unroll
    for (int j = 0; j < 4; ++j) {
        int qi = j * 16 + row;
        float c = cvec[b * BQ + qi];
        #pragma unroll
        for (int r = 0; r < 4; ++r) {
            int s = s0 + w * 16 + kg * 4 + r;
            scores[((size_t)b * SEQ + s) * BQ + qi] = acc[j][r] + c;
        }
    }
}

// ---------------------------------------------------------------------------
// softmax over s — partial stats
// ---------------------------------------------------------------------------
__global__ __launch_bounds__(256)
void sm_partial(const float* __restrict__ scores, float* __restrict__ pmax,
                float* __restrict__ psum)
{
    const int b  = blockIdx.y;
    const int ch = blockIdx.x;
    const int t  = threadIdx.x;
    const int qi = t & 63;
    const int g  = t >> 6;
    const float* sb = scores + ((size_t)b * SEQ + ch * 128) * BQ;
    float v[32];
    #pragma unroll
    for (int i = 0; i < 32; ++i)
        v[i] = sb[(size_t)(g + i * 4) * BQ + qi];
    float m = v[0];
    #pragma unroll
    for (int i = 1; i < 32; ++i) m = fmaxf(m, v[i]);
    __shared__ float red[4][64];
    red[g][qi] = m;
    __syncthreads();
    float M = fmaxf(fmaxf(red[0][qi], red[1][qi]), fmaxf(red[2][qi], red[3][qi]));
    float sum = 0.f;
    #pragma unroll
    for (int i = 0; i < 32; ++i) sum += __expf(v[i] - M);
    __syncthreads();
    red[g][qi] = sum;
    __syncthreads();
    if (g == 0) {
        float ssum = red[0][qi] + red[1][qi] + red[2][qi] + red[3][qi];
        pmax[((size_t)b * 32 + ch) * 64 + qi] = M;
        psum[((size_t)b * 32 + ch) * 64 + qi] = ssum;
    }
}

__global__ void sm_combine(const float* __restrict__ pmax,
                           const float* __restrict__ psum,
                           float* __restrict__ gstat)
{
    int b  = blockIdx.x;
    int qi = threadIdx.x; // 64
    float m = -1e30f;
    for (int c = 0; c < 32; ++c)
        m = fmaxf(m, pmax[((size_t)b * 32 + c) * 64 + qi]);
    float s = 0.f;
    for (int c = 0; c < 32; ++c)
        s += psum[((size_t)b * 32 + c) * 64 + qi] *
             __expf(pmax[((size_t)b * 32 + c) * 64 + qi] - m);
    gstat[(size_t)b * 64 + qi] = m;
    gstat[(size_t)(NB + b) * 64 + qi] = 1.f / s;
}

// normalize in place (f32, d_out) + write bf16 TRANSPOSED copy abfT[b][qi][s]
__global__ __launch_bounds__(256)
void sm_norm(float* __restrict__ attn, const float* __restrict__ gstat,
             __hip_bfloat16* __restrict__ abfT)
{
    __shared__ float tile[64][133];
    const int b  = blockIdx.y;
    const int ch = blockIdx.x;
    const int t  = threadIdx.x;
    const int qi = t & 63;
    const int g  = t >> 6;
    const float M   = gstat[(size_t)b * 64 + qi];
    const float inv = gstat[(size_t)(NB + b) * 64 + qi];
    float* sb = attn + ((size_t)b * SEQ + ch * 128) * BQ;
    #pragma unroll 8
    for (int i = 0; i < 32; ++i) {
        int sl = g + i * 4;
        size_t idx = (size_t)sl * BQ + qi;
        float w = __expf(sb[idx] - M) * inv;
        sb[idx] = w;
        tile[qi][sl] = w;
    }
    __syncthreads();
    const int qo = t >> 2;
    const int c  = (t & 3) * 32;
    __hip_bfloat16* dst = abfT + ((size_t)(b * BQ + qo)) * SEQ + ch * 128 + c;
    #pragma unroll
    for (int v = 0; v < 4; ++v) {
        bf16x8 w8;
        #pragma unroll
        for (int e = 0; e < 8; ++e)
            w8[e] = (__bf16)tile[qo][c + v * 8 + e];
        *reinterpret_cast<bf16x8*>(dst + v * 8) = w8;
    }
}

// ---------------------------------------------------------------------------
// Tpart[sc][b][qi][h] = sum_{s in chunk} abfT[b,qi,s] * values[b,s,h]
// MFMA: A=abfT (bf16), B=values (hi/lo). block: 64 qi x 128 h.
// grid (H/128, SC, NB)
// ---------------------------------------------------------------------------
__global__ __launch_bounds__(256)
void tmat_mfma(const __hip_bfloat16* __restrict__ abfT,
               const float* __restrict__ values,
               float* __restrict__ Tpart, int schunk)
{
    const int b   = blockIdx.z;
    const int sc  = blockIdx.y;
    const int h0  = blockIdx.x * 128;
    const int w   = threadIdx.x >> 6;   // wave: h-offset w*32
    const int l   = threadIdx.x & 63;
    const int row = l & 15;
    const int kg  = l >> 4;
    const int sbase = sc * schunk;

    const __hip_bfloat16* ap = abfT + ((size_t)b * BQ + row) * SEQ + sbase + kg * 8;
    const float* vp = values + ((size_t)b * SEQ + sbase + kg * 8) * H + h0 + w * 32 + row;

    f32x4 acc[4][2] = {};
    for (int k0 = 0; k0 < schunk; k0 += 32) {
        bf16x8 a[4];
        #pragma unroll
        for (int i = 0; i < 4; ++i)
            a[i] = *reinterpret_cast<const bf16x8*>(ap + (size_t)i * 16 * SEQ + k0);
        #pragma unroll
        for (int j = 0; j < 2; ++j) {
            float b8[8];
            const float* bp = vp + (size_t)k0 * H + j * 16;
            #pragma unroll
            for (int e = 0; e < 8; ++e) b8[e] = bp[(size_t)e * H];
            bf16x8 bhi, blo;
            split_bf16(b8, bhi, blo);
            #pragma unroll
            for (int i = 0; i < 4; ++i) {
                acc[i][j] = __builtin_amdgcn_mfma_f32_16x16x32_bf16(a[i], bhi, acc[i][j], 0, 0, 0);
                acc[i][j] = __builtin_amdgcn_mfma_f32_16x16x32_bf16(a[i], blo, acc[i][j], 0, 0, 0);
            }
        }
    }
    float* tp = Tpart + ((size_t)sc * NB + b) * BQ * H;
    #pragma unroll
    for (int i = 0; i < 4; ++i) {
        #pragma unroll
        for (int j = 0; j < 2; ++j) {
            int h = h0 + w * 32 + j * 16 + row;
            #pragma unroll
            for (int r = 0; r < 4; ++r) {
                int qi = i * 16 + kg * 4 + r;
                tp[(size_t)qi * H + h] = acc[i][j][r];
            }
        }
    }
}

// ---------------------------------------------------------------------------
extern "C" void kernel_launch(void* const* d_in, const int* in_sizes, int n_in,
                              void* d_out, int out_size, void* d_ws, size_t ws_size,
                              hipStream_t stream)
{
    const float* queries = (const float*)d_in[0];
    const float* keys    = (const float*)d_in[1];
    const float* values  = (const float*)d_in[2];
    const float* Wq = (const float*)d_in[3];
    const float* bq = (const float*)d_in[4];
    const float* Wk = (const float*)d_in[5];
    const float* bk = (const float*)d_in[6];
    const float* Wv = (const float*)d_in[7];
    const float* bv = (const float*)d_in[8];

    float* out     = (float*)d_out;
    float* context = out;                          // 16*64*1024 f32
    float* attn    = out + (size_t)NB * BQ * H;    // 16*4096*64 f32

    const int SC = (ws_size >= (43ull << 20)) ? 8 : 2;  // split-S factor
    const int schunk = SEQ / SC;

    char* ws = (char*)d_ws;
    // Tpart occupies [0, SC*4MB) and overlaps q/Nw (dead before tmat runs)
    float* q     = (float*)ws;                              // 4 MB
    float* Nw    = (float*)(ws + (4ull << 20));             // 4 MB
    float* Tpart = (float*)ws;                              // SC*4 MB
    __hip_bfloat16* abfT = (__hip_bfloat16*)(ws + (size_t)SC * (4ull << 20)); // 8 MB
    char* smalls = ws + (size_t)SC * (4ull << 20) + (8ull << 20);
    float* cvec  = (float*)smalls;                          // 4 KB
    float* gstat = (float*)(smalls + (64u << 10));          // 8 KB
    float* pmax  = (float*)(smalls + (128u << 10));         // 128 KB
    float* psum  = (float*)(smalls + (256u << 10));         // 128 KB

    const float scale = 0.03125f; // 1/sqrt(1024)

    // q = queries @ Wq^T + bq
    gemm_sum<true><<<dim3(16, 16), 256, 0, stream>>>(queries, 1, 0, Wq, bq, q, 1.0f);
    // N = (q @ Wk) * scale
    gemm_sum<false><<<dim3(16, 16), 256, 0, stream>>>(q, 1, 0, Wk, nullptr, Nw, scale);
    // c = (q . bk) * scale
    cvec_kernel<<<256, 256, 0, stream>>>(q, bk, cvec, scale);
    // scores -> attn region of d_out (f32-grade via hi/lo MFMA)
    scores_mfma<<<dim3(SEQ / 64, NB), 256, 0, stream>>>(keys, Nw, cvec, attn);
    // softmax over s
    sm_partial<<<dim3(32, NB), 256, 0, stream>>>(attn, pmax, psum);
    sm_combine<<<NB, 64, 0, stream>>>(pmax, psum, gstat);
    sm_norm<<<dim3(32, NB), 256, 0, stream>>>(attn, gstat, abfT);
    // T partials = attn^T @ values (MFMA, split-S)
    tmat_mfma<<<dim3(H / 128, SC, NB), 256, 0, stream>>>(abfT, values, Tpart, schunk);
    // context = (sum_p Tpart_p) @ Wv^T + bv
    gemm_sum<true><<<dim3(16, 16), 256, 0, stream>>>(
        Tpart, SC, (size_t)NB * BQ * H, Wv, bv, context, 1.0f);
}

// Round 3
// 399.947 us; speedup vs baseline: 2.4495x; 2.4495x over previous
//
#include <hip/hip_runtime.h>
#include <hip/hip_bf16.h>

#define H 1024
#define SEQ 4096
#define BQ 64   // Kq
#define NB 16   // batch

typedef float f32x4 __attribute__((ext_vector_type(4)));
typedef __bf16 bf16x8 __attribute__((ext_vector_type(8)));

__device__ __forceinline__ void split_bf16(const float* x, bf16x8& hi, bf16x8& lo)
{
    #pragma unroll
    for (int i = 0; i < 8; ++i) {
        float v = x[i];
        __bf16 h = (__bf16)v;
        hi[i] = h;
        lo[i] = (__bf16)(v - (float)h);
    }
}

// ---------------------------------------------------------------------------
// MFMA GEMM (BNK-true): C[1024x1024] = A @ B^T * scale + bias
// A[m*H+k], B[n*H+k]; f32-grade via hi/lo split (3 MFMAs).
// grid (16,16), block 256 (4 waves, each 16 m-rows x 64 n-cols)
// ---------------------------------------------------------------------------
__global__ __launch_bounds__(256)
void mfma_gemm_bt(const float* __restrict__ A, const float* __restrict__ Bm,
                  const float* __restrict__ bias, float* __restrict__ C, float scale)
{
    const int m0 = blockIdx.x * 64;
    const int n0 = blockIdx.y * 64;
    const int w   = threadIdx.x >> 6;
    const int l   = threadIdx.x & 63;
    const int row = l & 15;
    const int kg  = l >> 4;

    const float* ap = A + (size_t)(m0 + w * 16 + row) * H + kg * 8;
    const float* bp = Bm + (size_t)(n0 + row) * H + kg * 8;

    f32x4 acc[4] = {};
    for (int k0 = 0; k0 < H; k0 += 32) {
        float a8[8];
        *reinterpret_cast<float4*>(&a8[0]) = *reinterpret_cast<const float4*>(ap + k0);
        *reinterpret_cast<float4*>(&a8[4]) = *reinterpret_cast<const float4*>(ap + k0 + 4);
        bf16x8 ahi, alo;
        split_bf16(a8, ahi, alo);
        #pragma unroll
        for (int j = 0; j < 4; ++j) {
            float b8[8];
            const float* bjp = bp + (size_t)j * 16 * H + k0;
            *reinterpret_cast<float4*>(&b8[0]) = *reinterpret_cast<const float4*>(bjp);
            *reinterpret_cast<float4*>(&b8[4]) = *reinterpret_cast<const float4*>(bjp + 4);
            bf16x8 bhi, blo;
            split_bf16(b8, bhi, blo);
            acc[j] = __builtin_amdgcn_mfma_f32_16x16x32_bf16(ahi, bhi, acc[j], 0, 0, 0);
            acc[j] = __builtin_amdgcn_mfma_f32_16x16x32_bf16(ahi, blo, acc[j], 0, 0, 0);
            acc[j] = __builtin_amdgcn_mfma_f32_16x16x32_bf16(alo, bhi, acc[j], 0, 0, 0);
        }
    }
    #pragma unroll
    for (int j = 0; j < 4; ++j) {
        int n = n0 + j * 16 + row;
        float bb = bias ? bias[n] : 0.f;
        #pragma unroll
        for (int r = 0; r < 4; ++r) {
            int m = m0 + w * 16 + kg * 4 + r;
            C[(size_t)m * H + n] = acc[j][r] * scale + bb;
        }
    }
}

// ---------------------------------------------------------------------------
// VALU GEMM (BNK-false): C = A @ B * scale,  B[k*H+n]  (used for N = q @ Wk)
// ---------------------------------------------------------------------------
__global__ __launch_bounds__(256)
void gemm_bn(const float* __restrict__ A, const float* __restrict__ Bm,
             float* __restrict__ C, float scale)
{
    __shared__ float As[32][68];
    __shared__ float Bs[32][68];
    const int m0 = blockIdx.x * 64;
    const int n0 = blockIdx.y * 64;
    const int t  = threadIdx.x;
    const int tn = t & 15;
    const int tm = t >> 4;
    float acc[4][4] = {};

    for (int k0 = 0; k0 < H; k0 += 32) {
        {
            int kk = t & 31;
            int mb = (t >> 5) * 8;
            #pragma unroll
            for (int r = 0; r < 8; ++r)
                As[kk][mb + r] = A[(size_t)(m0 + mb + r) * H + k0 + kk];
        }
        {
            int n  = t & 63;
            int kb = (t >> 6) * 8;
            #pragma unroll
            for (int r = 0; r < 8; ++r)
                Bs[kb + r][n] = Bm[(size_t)(k0 + kb + r) * H + n0 + n];
        }
        __syncthreads();
        #pragma unroll 8
        for (int kk = 0; kk < 32; ++kk) {
            float4 a4 = *reinterpret_cast<const float4*>(&As[kk][tm * 4]);
            float4 b4 = *reinterpret_cast<const float4*>(&Bs[kk][tn * 4]);
            float av[4] = {a4.x, a4.y, a4.z, a4.w};
            float bv2[4] = {b4.x, b4.y, b4.z, b4.w};
            #pragma unroll
            for (int i = 0; i < 4; ++i)
                #pragma unroll
                for (int j = 0; j < 4; ++j)
                    acc[i][j] += av[i] * bv2[j];
        }
        __syncthreads();
    }

    #pragma unroll
    for (int i = 0; i < 4; ++i) {
        int m = m0 + tm * 4 + i;
        float4 o;
        float* po = &o.x;
        #pragma unroll
        for (int j = 0; j < 4; ++j)
            po[j] = acc[i][j] * scale;
        *reinterpret_cast<float4*>(&C[(size_t)m * H + n0 + tn * 4]) = o;
    }
}

// ---------------------------------------------------------------------------
// c[b,qi] = scale * dot(q[b,qi,:], bk)
// ---------------------------------------------------------------------------
__global__ __launch_bounds__(256)
void cvec_kernel(const float* __restrict__ q, const float* __restrict__ bk,
                 float* __restrict__ cvec, float scale)
{
    int r = blockIdx.x * 4 + (threadIdx.x >> 6);
    int l = threadIdx.x & 63;
    float s = 0.f;
    #pragma unroll
    for (int i = 0; i < 16; ++i)
        s += q[(size_t)r * H + l + 64 * i] * bk[l + 64 * i];
    #pragma unroll
    for (int off = 32; off; off >>= 1)
        s += __shfl_down(s, off);
    if (l == 0) cvec[r] = s * scale;
}

// ---------------------------------------------------------------------------
// scores[b,s,qi] = sum_h keys[b,s,h]*N[b,qi,h] + c[b,qi]  (MFMA, hi/lo)
// ---------------------------------------------------------------------------
__global__ __launch_bounds__(256)
void scores_mfma(const float* __restrict__ keys, const float* __restrict__ Nw,
                 const float* __restrict__ cvec, float* __restrict__ scores)
{
    const int b   = blockIdx.y;
    const int s0  = blockIdx.x * 64;
    const int w   = threadIdx.x >> 6;
    const int l   = threadIdx.x & 63;
    const int row = l & 15;
    const int kg  = l >> 4;

    const float* ka = keys + ((size_t)b * SEQ + s0 + w * 16 + row) * H + kg * 8;
    const float* nb = Nw + (size_t)b * BQ * H + (size_t)row * H + kg * 8;

    f32x4 acc[4] = {};
    for (int k0 = 0; k0 < H; k0 += 32) {
        float a8[8];
        *reinterpret_cast<float4*>(&a8[0]) = *reinterpret_cast<const float4*>(ka + k0);
        *reinterpret_cast<float4*>(&a8[4]) = *reinterpret_cast<const float4*>(ka + k0 + 4);
        bf16x8 ahi, alo;
        split_bf16(a8, ahi, alo);
        #pragma unroll
        for (int j = 0; j < 4; ++j) {
            float b8[8];
            const float* bp = nb + (size_t)j * 16 * H + k0;
            *reinterpret_cast<float4*>(&b8[0]) = *reinterpret_cast<const float4*>(bp);
            *reinterpret_cast<float4*>(&b8[4]) = *reinterpret_cast<const float4*>(bp + 4);
            bf16x8 bhi, blo;
            split_bf16(b8, bhi, blo);
            acc[j] = __builtin_amdgcn_mfma_f32_16x16x32_bf16(ahi, bhi, acc[j], 0, 0, 0);
            acc[j] = __builtin_amdgcn_mfma_f32_16x16x32_bf16(ahi, blo, acc[j], 0, 0, 0);
            acc[j] = __builtin_amdgcn_mfma_f32_16x16x32_bf16(alo, bhi, acc[j], 0, 0, 0);
        }
    }
    #pragma unroll
    for (int j = 0; j < 4; ++j) {
        int qi = j * 16 + row;
        float c = cvec[b * BQ + qi];
        #pragma unroll
        for (int r = 0; r < 4; ++r) {
            int s = s0 + w * 16 + kg * 4 + r;
            scores[((size_t)b * SEQ + s) * BQ + qi] = acc[j][r] + c;
        }
    }
}

// ---------------------------------------------------------------------------
// softmax over s — partial stats
// ---------------------------------------------------------------------------
__global__ __launch_bounds__(256)
void sm_partial(const float* __restrict__ scores, float* __restrict__ pmax,
                float* __restrict__ psum)
{
    const int b  = blockIdx.y;
    const int ch = blockIdx.x;
    const int t  = threadIdx.x;
    const int qi = t & 63;
    const int g  = t >> 6;
    const float* sb = scores + ((size_t)b * SEQ + ch * 128) * BQ;
    float v[32];
    #pragma unroll
    for (int i = 0; i < 32; ++i)
        v[i] = sb[(size_t)(g + i * 4) * BQ + qi];
    float m = v[0];
    #pragma unroll
    for (int i = 1; i < 32; ++i) m = fmaxf(m, v[i]);
    __shared__ float red[4][64];
    red[g][qi] = m;
    __syncthreads();
    float M = fmaxf(fmaxf(red[0][qi], red[1][qi]), fmaxf(red[2][qi], red[3][qi]));
    float sum = 0.f;
    #pragma unroll
    for (int i = 0; i < 32; ++i) sum += __expf(v[i] - M);
    __syncthreads();
    red[g][qi] = sum;
    __syncthreads();
    if (g == 0) {
        float ssum = red[0][qi] + red[1][qi] + red[2][qi] + red[3][qi];
        pmax[((size_t)b * 32 + ch) * 64 + qi] = M;
        psum[((size_t)b * 32 + ch) * 64 + qi] = ssum;
    }
}

__global__ void sm_combine(const float* __restrict__ pmax,
                           const float* __restrict__ psum,
                           float* __restrict__ gstat)
{
    int b  = blockIdx.x;
    int qi = threadIdx.x; // 64
    float m = -1e30f;
    for (int c = 0; c < 32; ++c)
        m = fmaxf(m, pmax[((size_t)b * 32 + c) * 64 + qi]);
    float s = 0.f;
    for (int c = 0; c < 32; ++c)
        s += psum[((size_t)b * 32 + c) * 64 + qi] *
             __expf(pmax[((size_t)b * 32 + c) * 64 + qi] - m);
    gstat[(size_t)b * 64 + qi] = m;
    gstat[(size_t)(NB + b) * 64 + qi] = 1.f / s;
}

// normalize in place (f32, d_out) + write bf16 TRANSPOSED copy abfT[b][qi][s]
__global__ __launch_bounds__(256)
void sm_norm(float* __restrict__ attn, const float* __restrict__ gstat,
             __hip_bfloat16* __restrict__ abfT)
{
    __shared__ float tile[64][133];
    const int b  = blockIdx.y;
    const int ch = blockIdx.x;
    const int t  = threadIdx.x;
    const int qi = t & 63;
    const int g  = t >> 6;
    const float M   = gstat[(size_t)b * 64 + qi];
    const float inv = gstat[(size_t)(NB + b) * 64 + qi];
    float* sb = attn + ((size_t)b * SEQ + ch * 128) * BQ;
    #pragma unroll 8
    for (int i = 0; i < 32; ++i) {
        int sl = g + i * 4;
        size_t idx = (size_t)sl * BQ + qi;
        float w = __expf(sb[idx] - M) * inv;
        sb[idx] = w;
        tile[qi][sl] = w;
    }
    __syncthreads();
    const int qo = t >> 2;
    const int c  = (t & 3) * 32;
    __hip_bfloat16* dst = abfT + ((size_t)(b * BQ + qo)) * SEQ + ch * 128 + c;
    #pragma unroll
    for (int v = 0; v < 4; ++v) {
        bf16x8 w8;
        #pragma unroll
        for (int e = 0; e < 8; ++e)
            w8[e] = (__bf16)tile[qo][c + v * 8 + e];
        *reinterpret_cast<bf16x8*>(dst + v * 8) = w8;
    }
}

// ---------------------------------------------------------------------------
// Tpart[sc][b][qi][h] = sum_{s in chunk} abfT[b,qi,s] * values[b,s,h]
// ---------------------------------------------------------------------------
__global__ __launch_bounds__(256)
void tmat_mfma(const __hip_bfloat16* __restrict__ abfT,
               const float* __restrict__ values,
               float* __restrict__ Tpart, int schunk)
{
    const int b   = blockIdx.z;
    const int sc  = blockIdx.y;
    const int h0  = blockIdx.x * 128;
    const int w   = threadIdx.x >> 6;
    const int l   = threadIdx.x & 63;
    const int row = l & 15;
    const int kg  = l >> 4;
    const int sbase = sc * schunk;

    const __hip_bfloat16* ap = abfT + ((size_t)b * BQ + row) * SEQ + sbase + kg * 8;
    const float* vp = values + ((size_t)b * SEQ + sbase + kg * 8) * H + h0 + w * 32 + row;

    f32x4 acc[4][2] = {};
    for (int k0 = 0; k0 < schunk; k0 += 32) {
        bf16x8 a[4];
        #pragma unroll
        for (int i = 0; i < 4; ++i)
            a[i] = *reinterpret_cast<const bf16x8*>(ap + (size_t)i * 16 * SEQ + k0);
        #pragma unroll
        for (int j = 0; j < 2; ++j) {
            float b8[8];
            const float* bp = vp + (size_t)k0 * H + j * 16;
            #pragma unroll
            for (int e = 0; e < 8; ++e) b8[e] = bp[(size_t)e * H];
            bf16x8 bhi, blo;
            split_bf16(b8, bhi, blo);
            #pragma unroll
            for (int i = 0; i < 4; ++i) {
                acc[i][j] = __builtin_amdgcn_mfma_f32_16x16x32_bf16(a[i], bhi, acc[i][j], 0, 0, 0);
                acc[i][j] = __builtin_amdgcn_mfma_f32_16x16x32_bf16(a[i], blo, acc[i][j], 0, 0, 0);
            }
        }
    }
    float* tp = Tpart + ((size_t)sc * NB + b) * BQ * H;
    #pragma unroll
    for (int i = 0; i < 4; ++i) {
        #pragma unroll
        for (int j = 0; j < 2; ++j) {
            int h = h0 + w * 32 + j * 16 + row;
            #pragma unroll
            for (int r = 0; r < 4; ++r) {
                int qi = i * 16 + kg * 4 + r;
                tp[(size_t)qi * H + h] = acc[i][j][r];
            }
        }
    }
}

// ---------------------------------------------------------------------------
// In-place partial reduction: Tpart[0][i] = sum_p Tpart[p][i]
// ---------------------------------------------------------------------------
template<int SC>
__global__ __launch_bounds__(256)
void tsum_kernel(float* __restrict__ Tpart)
{
    const size_t stride = (size_t)NB * BQ * H;
    size_t i = ((size_t)blockIdx.x * 256 + threadIdx.x) * 4;
    f32x4 s = *reinterpret_cast<const f32x4*>(Tpart + i);
    #pragma unroll
    for (int p = 1; p < SC; ++p)
        s += *reinterpret_cast<const f32x4*>(Tpart + p * stride + i);
    *reinterpret_cast<f32x4*>(Tpart + i) = s;
}

// ---------------------------------------------------------------------------
extern "C" void kernel_launch(void* const* d_in, const int* in_sizes, int n_in,
                              void* d_out, int out_size, void* d_ws, size_t ws_size,
                              hipStream_t stream)
{
    const float* queries = (const float*)d_in[0];
    const float* keys    = (const float*)d_in[1];
    const float* values  = (const float*)d_in[2];
    const float* Wq = (const float*)d_in[3];
    const float* bq = (const float*)d_in[4];
    const float* Wk = (const float*)d_in[5];
    const float* bk = (const float*)d_in[6];
    const float* Wv = (const float*)d_in[7];
    const float* bv = (const float*)d_in[8];

    float* out     = (float*)d_out;
    float* context = out;                          // 16*64*1024 f32
    float* attn    = out + (size_t)NB * BQ * H;    // 16*4096*64 f32

    const int SC = (ws_size >= (41ull << 20)) ? 8 : 2;
    const int schunk = SEQ / SC;

    char* ws = (char*)d_ws;
    float* q     = (float*)ws;                              // 4 MB
    float* Nw    = (float*)(ws + (4ull << 20));             // 4 MB
    float* Tpart = (float*)ws;                              // SC*4 MB (overlaps q/Nw, dead by then)
    __hip_bfloat16* abfT = (__hip_bfloat16*)(ws + (size_t)SC * (4ull << 20)); // 8 MB
    char* smalls = ws + (size_t)SC * (4ull << 20) + (8ull << 20);
    float* cvec  = (float*)smalls;                          // 4 KB
    float* gstat = (float*)(smalls + (64u << 10));          // 8 KB
    float* pmax  = (float*)(smalls + (128u << 10));         // 128 KB
    float* psum  = (float*)(smalls + (256u << 10));         // 128 KB

    const float scale = 0.03125f; // 1/sqrt(1024)

    // q = queries @ Wq^T + bq   (MFMA hi/lo)
    mfma_gemm_bt<<<dim3(16, 16), 256, 0, stream>>>(queries, Wq, bq, q, 1.0f);
    // N = (q @ Wk) * scale      (VALU, B in [k][n] layout)
    gemm_bn<<<dim3(16, 16), 256, 0, stream>>>(q, Wk, Nw, scale);
    // c = (q . bk) * scale
    cvec_kernel<<<256, 256, 0, stream>>>(q, bk, cvec, scale);
    // scores -> attn region of d_out
    scores_mfma<<<dim3(SEQ / 64, NB), 256, 0, stream>>>(keys, Nw, cvec, attn);
    // softmax over s
    sm_partial<<<dim3(32, NB), 256, 0, stream>>>(attn, pmax, psum);
    sm_combine<<<NB, 64, 0, stream>>>(pmax, psum, gstat);
    sm_norm<<<dim3(32, NB), 256, 0, stream>>>(attn, gstat, abfT);
    // T partials = attn^T @ values (MFMA, split-S)
    tmat_mfma<<<dim3(H / 128, SC, NB), 256, 0, stream>>>(abfT, values, Tpart, schunk);
    // Tsum (in place into partial 0)
    if (SC == 8) tsum_kernel<8><<<1024, 256, 0, stream>>>(Tpart);
    else         tsum_kernel<2><<<1024, 256, 0, stream>>>(Tpart);
    // context = Tsum @ Wv^T + bv  (MFMA hi/lo)
    mfma_gemm_bt<<<dim3(16, 16), 256, 0, stream>>>(Tpart, Wv, bv, context, 1.0f);
}

// Round 4
// 372.986 us; speedup vs baseline: 2.6265x; 1.0723x over previous
//
#include <hip/hip_runtime.h>
#include <hip/hip_bf16.h>

#define H 1024
#define SEQ 4096
#define BQ 64   // Kq
#define NB 16   // batch

typedef float f32x4 __attribute__((ext_vector_type(4)));
typedef __bf16 bf16x8 __attribute__((ext_vector_type(8)));

__device__ __forceinline__ void split_bf16(const float* x, bf16x8& hi, bf16x8& lo)
{
    #pragma unroll
    for (int i = 0; i < 8; ++i) {
        float v = x[i];
        __bf16 h = (__bf16)v;
        hi[i] = h;
        lo[i] = (__bf16)(v - (float)h);
    }
}

// ---------------------------------------------------------------------------
// MFMA GEMM (BNK-true): C[1024x1024] = A @ B^T * scale + bias
// A[m*H+k], B[n*H+k]; f32-grade via hi/lo split (3 MFMAs).
// ---------------------------------------------------------------------------
__global__ __launch_bounds__(256)
void mfma_gemm_bt(const float* __restrict__ A, const float* __restrict__ Bm,
                  const float* __restrict__ bias, float* __restrict__ C, float scale)
{
    const int m0 = blockIdx.x * 64;
    const int n0 = blockIdx.y * 64;
    const int w   = threadIdx.x >> 6;
    const int l   = threadIdx.x & 63;
    const int row = l & 15;
    const int kg  = l >> 4;

    const float* ap = A + (size_t)(m0 + w * 16 + row) * H + kg * 8;
    const float* bp = Bm + (size_t)(n0 + row) * H + kg * 8;

    f32x4 acc[4] = {};
    for (int k0 = 0; k0 < H; k0 += 32) {
        float a8[8];
        *reinterpret_cast<float4*>(&a8[0]) = *reinterpret_cast<const float4*>(ap + k0);
        *reinterpret_cast<float4*>(&a8[4]) = *reinterpret_cast<const float4*>(ap + k0 + 4);
        bf16x8 ahi, alo;
        split_bf16(a8, ahi, alo);
        #pragma unroll
        for (int j = 0; j < 4; ++j) {
            float b8[8];
            const float* bjp = bp + (size_t)j * 16 * H + k0;
            *reinterpret_cast<float4*>(&b8[0]) = *reinterpret_cast<const float4*>(bjp);
            *reinterpret_cast<float4*>(&b8[4]) = *reinterpret_cast<const float4*>(bjp + 4);
            bf16x8 bhi, blo;
            split_bf16(b8, bhi, blo);
            acc[j] = __builtin_amdgcn_mfma_f32_16x16x32_bf16(ahi, bhi, acc[j], 0, 0, 0);
            acc[j] = __builtin_amdgcn_mfma_f32_16x16x32_bf16(ahi, blo, acc[j], 0, 0, 0);
            acc[j] = __builtin_amdgcn_mfma_f32_16x16x32_bf16(alo, bhi, acc[j], 0, 0, 0);
        }
    }
    #pragma unroll
    for (int j = 0; j < 4; ++j) {
        int n = n0 + j * 16 + row;
        float bb = bias ? bias[n] : 0.f;
        #pragma unroll
        for (int r = 0; r < 4; ++r) {
            int m = m0 + w * 16 + kg * 4 + r;
            C[(size_t)m * H + n] = acc[j][r] * scale + bb;
        }
    }
}

// ---------------------------------------------------------------------------
// N-proj MFMA: N = (q @ Wk) * scale, emitted pre-split as bf16 hi/lo.
// A[m*H+k]=q (contig). B[k][n]=Wk (n contig, k strided -> per-elem loads).
// Output Nhi/Nlo row-major [m][n] bf16.
// ---------------------------------------------------------------------------
__global__ __launch_bounds__(256)
void ngemm_mfma(const float* __restrict__ q, const float* __restrict__ Wk,
                __bf16* __restrict__ Nhi, __bf16* __restrict__ Nlo, float scale)
{
    const int m0 = blockIdx.x * 64;
    const int n0 = blockIdx.y * 64;
    const int w   = threadIdx.x >> 6;
    const int l   = threadIdx.x & 63;
    const int row = l & 15;
    const int kg  = l >> 4;

    const float* ap = q + (size_t)(m0 + w * 16 + row) * H + kg * 8;
    const float* bp = Wk + (size_t)(kg * 8) * H + n0 + row;

    f32x4 acc[4] = {};
    for (int k0 = 0; k0 < H; k0 += 32) {
        float a8[8];
        *reinterpret_cast<float4*>(&a8[0]) = *reinterpret_cast<const float4*>(ap + k0);
        *reinterpret_cast<float4*>(&a8[4]) = *reinterpret_cast<const float4*>(ap + k0 + 4);
        bf16x8 ahi, alo;
        split_bf16(a8, ahi, alo);
        #pragma unroll
        for (int j = 0; j < 4; ++j) {
            float b8[8];
            #pragma unroll
            for (int e = 0; e < 8; ++e)
                b8[e] = bp[(size_t)(k0 + e) * H + j * 16];
            bf16x8 bhi, blo;
            split_bf16(b8, bhi, blo);
            acc[j] = __builtin_amdgcn_mfma_f32_16x16x32_bf16(ahi, bhi, acc[j], 0, 0, 0);
            acc[j] = __builtin_amdgcn_mfma_f32_16x16x32_bf16(ahi, blo, acc[j], 0, 0, 0);
            acc[j] = __builtin_amdgcn_mfma_f32_16x16x32_bf16(alo, bhi, acc[j], 0, 0, 0);
        }
    }
    #pragma unroll
    for (int j = 0; j < 4; ++j) {
        int n = n0 + j * 16 + row;
        #pragma unroll
        for (int r = 0; r < 4; ++r) {
            int m = m0 + w * 16 + kg * 4 + r;
            float v = acc[j][r] * scale;
            __bf16 hi = (__bf16)v;
            Nhi[(size_t)m * H + n] = hi;
            Nlo[(size_t)m * H + n] = (__bf16)(v - (float)hi);
        }
    }
}

// ---------------------------------------------------------------------------
// c[b,qi] = scale * dot(q[b,qi,:], bk)
// ---------------------------------------------------------------------------
__global__ __launch_bounds__(256)
void cvec_kernel(const float* __restrict__ q, const float* __restrict__ bk,
                 float* __restrict__ cvec, float scale)
{
    int r = blockIdx.x * 4 + (threadIdx.x >> 6);
    int l = threadIdx.x & 63;
    float s = 0.f;
    #pragma unroll
    for (int i = 0; i < 16; ++i)
        s += q[(size_t)r * H + l + 64 * i] * bk[l + 64 * i];
    #pragma unroll
    for (int off = 32; off; off >>= 1)
        s += __shfl_down(s, off);
    if (l == 0) cvec[r] = s * scale;
}

// ---------------------------------------------------------------------------
// scores[b,s,qi] = sum_h keys[b,s,h]*N[b,qi,h] + c[b,qi]
// A=keys (split on load), B=pre-split Nhi/Nlo (direct bf16x8 loads)
// ---------------------------------------------------------------------------
__global__ __launch_bounds__(256)
void scores_mfma(const float* __restrict__ keys,
                 const __bf16* __restrict__ Nhi, const __bf16* __restrict__ Nlo,
                 const float* __restrict__ cvec, float* __restrict__ scores)
{
    const int b   = blockIdx.y;
    const int s0  = blockIdx.x * 64;
    const int w   = threadIdx.x >> 6;
    const int l   = threadIdx.x & 63;
    const int row = l & 15;
    const int kg  = l >> 4;

    const float* ka = keys + ((size_t)b * SEQ + s0 + w * 16 + row) * H + kg * 8;
    const size_t nbase = ((size_t)b * BQ + row) * H + kg * 8;

    f32x4 acc[4] = {};
    for (int k0 = 0; k0 < H; k0 += 32) {
        float a8[8];
        *reinterpret_cast<float4*>(&a8[0]) = *reinterpret_cast<const float4*>(ka + k0);
        *reinterpret_cast<float4*>(&a8[4]) = *reinterpret_cast<const float4*>(ka + k0 + 4);
        bf16x8 ahi, alo;
        split_bf16(a8, ahi, alo);
        #pragma unroll
        for (int j = 0; j < 4; ++j) {
            size_t off = nbase + (size_t)j * 16 * H + k0;
            bf16x8 bhi = *reinterpret_cast<const bf16x8*>(Nhi + off);
            bf16x8 blo = *reinterpret_cast<const bf16x8*>(Nlo + off);
            acc[j] = __builtin_amdgcn_mfma_f32_16x16x32_bf16(ahi, bhi, acc[j], 0, 0, 0);
            acc[j] = __builtin_amdgcn_mfma_f32_16x16x32_bf16(ahi, blo, acc[j], 0, 0, 0);
            acc[j] = __builtin_amdgcn_mfma_f32_16x16x32_bf16(alo, bhi, acc[j], 0, 0, 0);
        }
    }
    #pragma unroll
    for (int j = 0; j < 4; ++j) {
        int qi = j * 16 + row;
        float c = cvec[b * BQ + qi];
        #pragma unroll
        for (int r = 0; r < 4; ++r) {
            int s = s0 + w * 16 + kg * 4 + r;
            scores[((size_t)b * SEQ + s) * BQ + qi] = acc[j][r] + c;
        }
    }
}

// ---------------------------------------------------------------------------
// softmax over s — partial stats
// ---------------------------------------------------------------------------
__global__ __launch_bounds__(256)
void sm_partial(const float* __restrict__ scores, float* __restrict__ pmax,
                float* __restrict__ psum)
{
    const int b  = blockIdx.y;
    const int ch = blockIdx.x;
    const int t  = threadIdx.x;
    const int qi = t & 63;
    const int g  = t >> 6;
    const float* sb = scores + ((size_t)b * SEQ + ch * 128) * BQ;
    float v[32];
    #pragma unroll
    for (int i = 0; i < 32; ++i)
        v[i] = sb[(size_t)(g + i * 4) * BQ + qi];
    float m = v[0];
    #pragma unroll
    for (int i = 1; i < 32; ++i) m = fmaxf(m, v[i]);
    __shared__ float red[4][64];
    red[g][qi] = m;
    __syncthreads();
    float M = fmaxf(fmaxf(red[0][qi], red[1][qi]), fmaxf(red[2][qi], red[3][qi]));
    float sum = 0.f;
    #pragma unroll
    for (int i = 0; i < 32; ++i) sum += __expf(v[i] - M);
    __syncthreads();
    red[g][qi] = sum;
    __syncthreads();
    if (g == 0) {
        float ssum = red[0][qi] + red[1][qi] + red[2][qi] + red[3][qi];
        pmax[((size_t)b * 32 + ch) * 64 + qi] = M;
        psum[((size_t)b * 32 + ch) * 64 + qi] = ssum;
    }
}

__global__ void sm_combine(const float* __restrict__ pmax,
                           const float* __restrict__ psum,
                           float* __restrict__ gstat)
{
    int b  = blockIdx.x;
    int qi = threadIdx.x; // 64
    float m = -1e30f;
    for (int c = 0; c < 32; ++c)
        m = fmaxf(m, pmax[((size_t)b * 32 + c) * 64 + qi]);
    float s = 0.f;
    for (int c = 0; c < 32; ++c)
        s += psum[((size_t)b * 32 + c) * 64 + qi] *
             __expf(pmax[((size_t)b * 32 + c) * 64 + qi] - m);
    gstat[(size_t)b * 64 + qi] = m;
    gstat[(size_t)(NB + b) * 64 + qi] = 1.f / s;
}

// normalize in place (f32, d_out) + write bf16 TRANSPOSED copy abfT[b][qi][s]
__global__ __launch_bounds__(256)
void sm_norm(float* __restrict__ attn, const float* __restrict__ gstat,
             __hip_bfloat16* __restrict__ abfT)
{
    __shared__ float tile[64][133];
    const int b  = blockIdx.y;
    const int ch = blockIdx.x;
    const int t  = threadIdx.x;
    const int qi = t & 63;
    const int g  = t >> 6;
    const float M   = gstat[(size_t)b * 64 + qi];
    const float inv = gstat[(size_t)(NB + b) * 64 + qi];
    float* sb = attn + ((size_t)b * SEQ + ch * 128) * BQ;
    #pragma unroll 8
    for (int i = 0; i < 32; ++i) {
        int sl = g + i * 4;
        size_t idx = (size_t)sl * BQ + qi;
        float w = __expf(sb[idx] - M) * inv;
        sb[idx] = w;
        tile[qi][sl] = w;
    }
    __syncthreads();
    const int qo = t >> 2;
    const int c  = (t & 3) * 32;
    __hip_bfloat16* dst = abfT + ((size_t)(b * BQ + qo)) * SEQ + ch * 128 + c;
    #pragma unroll
    for (int v = 0; v < 4; ++v) {
        bf16x8 w8;
        #pragma unroll
        for (int e = 0; e < 8; ++e)
            w8[e] = (__bf16)tile[qo][c + v * 8 + e];
        *reinterpret_cast<bf16x8*>(dst + v * 8) = w8;
    }
}

// ---------------------------------------------------------------------------
// Tpart[sc][b][qi][h] = sum_{s in chunk} abfT[b,qi,s] * values[b,s,h]
// ---------------------------------------------------------------------------
__global__ __launch_bounds__(256)
void tmat_mfma(const __hip_bfloat16* __restrict__ abfT,
               const float* __restrict__ values,
               float* __restrict__ Tpart, int schunk)
{
    const int b   = blockIdx.z;
    const int sc  = blockIdx.y;
    const int h0  = blockIdx.x * 128;
    const int w   = threadIdx.x >> 6;
    const int l   = threadIdx.x & 63;
    const int row = l & 15;
    const int kg  = l >> 4;
    const int sbase = sc * schunk;

    const __hip_bfloat16* ap = abfT + ((size_t)b * BQ + row) * SEQ + sbase + kg * 8;
    const float* vp = values + ((size_t)b * SEQ + sbase + kg * 8) * H + h0 + w * 32 + row;

    f32x4 acc[4][2] = {};
    for (int k0 = 0; k0 < schunk; k0 += 32) {
        bf16x8 a[4];
        #pragma unroll
        for (int i = 0; i < 4; ++i)
            a[i] = *reinterpret_cast<const bf16x8*>(ap + (size_t)i * 16 * SEQ + k0);
        #pragma unroll
        for (int j = 0; j < 2; ++j) {
            float b8[8];
            const float* bp = vp + (size_t)k0 * H + j * 16;
            #pragma unroll
            for (int e = 0; e < 8; ++e) b8[e] = bp[(size_t)e * H];
            bf16x8 bhi, blo;
            split_bf16(b8, bhi, blo);
            #pragma unroll
            for (int i = 0; i < 4; ++i) {
                acc[i][j] = __builtin_amdgcn_mfma_f32_16x16x32_bf16(a[i], bhi, acc[i][j], 0, 0, 0);
                acc[i][j] = __builtin_amdgcn_mfma_f32_16x16x32_bf16(a[i], blo, acc[i][j], 0, 0, 0);
            }
        }
    }
    float* tp = Tpart + ((size_t)sc * NB + b) * BQ * H;
    #pragma unroll
    for (int i = 0; i < 4; ++i) {
        #pragma unroll
        for (int j = 0; j < 2; ++j) {
            int h = h0 + w * 32 + j * 16 + row;
            #pragma unroll
            for (int r = 0; r < 4; ++r) {
                int qi = i * 16 + kg * 4 + r;
                tp[(size_t)qi * H + h] = acc[i][j][r];
            }
        }
    }
}

// ---------------------------------------------------------------------------
// In-place partial reduction: Tpart[0][i] = sum_p Tpart[p][i]
// ---------------------------------------------------------------------------
template<int SC>
__global__ __launch_bounds__(256)
void tsum_kernel(float* __restrict__ Tpart)
{
    const size_t stride = (size_t)NB * BQ * H;
    size_t i = ((size_t)blockIdx.x * 256 + threadIdx.x) * 4;
    f32x4 s = *reinterpret_cast<const f32x4*>(Tpart + i);
    #pragma unroll
    for (int p = 1; p < SC; ++p)
        s += *reinterpret_cast<const f32x4*>(Tpart + p * stride + i);
    *reinterpret_cast<f32x4*>(Tpart + i) = s;
}

// ---------------------------------------------------------------------------
extern "C" void kernel_launch(void* const* d_in, const int* in_sizes, int n_in,
                              void* d_out, int out_size, void* d_ws, size_t ws_size,
                              hipStream_t stream)
{
    const float* queries = (const float*)d_in[0];
    const float* keys    = (const float*)d_in[1];
    const float* values  = (const float*)d_in[2];
    const float* Wq = (const float*)d_in[3];
    const float* bq = (const float*)d_in[4];
    const float* Wk = (const float*)d_in[5];
    const float* bk = (const float*)d_in[6];
    const float* Wv = (const float*)d_in[7];
    const float* bv = (const float*)d_in[8];

    float* out     = (float*)d_out;
    float* context = out;                          // 16*64*1024 f32
    float* attn    = out + (size_t)NB * BQ * H;    // 16*4096*64 f32

    const int SC = (ws_size >= (41ull << 20)) ? 8 : 2;
    const int schunk = SEQ / SC;

    char* ws = (char*)d_ws;
    float* q     = (float*)ws;                              // 4 MB  [0,4)
    __bf16* Nhi  = (__bf16*)(ws + (4ull << 20));            // 2 MB  [4,6)
    __bf16* Nlo  = (__bf16*)(ws + (6ull << 20));            // 2 MB  [6,8)
    float* Tpart = (float*)ws;                              // SC*4 MB (overlaps q/N, dead by then)
    __hip_bfloat16* abfT = (__hip_bfloat16*)(ws + (size_t)SC * (4ull << 20)); // 8 MB
    char* smalls = ws + (size_t)SC * (4ull << 20) + (8ull << 20);
    float* cvec  = (float*)smalls;                          // 4 KB
    float* gstat = (float*)(smalls + (64u << 10));          // 8 KB
    float* pmax  = (float*)(smalls + (128u << 10));         // 128 KB
    float* psum  = (float*)(smalls + (256u << 10));         // 128 KB

    const float scale = 0.03125f; // 1/sqrt(1024)

    // q = queries @ Wq^T + bq   (MFMA hi/lo)
    mfma_gemm_bt<<<dim3(16, 16), 256, 0, stream>>>(queries, Wq, bq, q, 1.0f);
    // N = (q @ Wk) * scale  -> pre-split bf16 hi/lo
    ngemm_mfma<<<dim3(16, 16), 256, 0, stream>>>(q, Wk, Nhi, Nlo, scale);
    // c = (q . bk) * scale
    cvec_kernel<<<256, 256, 0, stream>>>(q, bk, cvec, scale);
    // scores -> attn region of d_out
    scores_mfma<<<dim3(SEQ / 64, NB), 256, 0, stream>>>(keys, Nhi, Nlo, cvec, attn);
    // softmax over s
    sm_partial<<<dim3(32, NB), 256, 0, stream>>>(attn, pmax, psum);
    sm_combine<<<NB, 64, 0, stream>>>(pmax, psum, gstat);
    sm_norm<<<dim3(32, NB), 256, 0, stream>>>(attn, gstat, abfT);
    // T partials = attn^T @ values (MFMA, split-S)
    tmat_mfma<<<dim3(H / 128, SC, NB), 256, 0, stream>>>(abfT, values, Tpart, schunk);
    // Tsum (in place into partial 0)
    if (SC == 8) tsum_kernel<8><<<1024, 256, 0, stream>>>(Tpart);
    else         tsum_kernel<2><<<1024, 256, 0, stream>>>(Tpart);
    // context = Tsum @ Wv^T + bv  (MFMA hi/lo)
    mfma_gemm_bt<<<dim3(16, 16), 256, 0, stream>>>(Tpart, Wv, bv, context, 1.0f);
}

// Round 5
// 299.706 us; speedup vs baseline: 3.2687x; 1.2445x over previous
//
#include <hip/hip_runtime.h>
#include <hip/hip_bf16.h>

#define H 1024
#define SEQ 4096
#define BQ 64   // Kq
#define NB 16   // batch

typedef float f32x4 __attribute__((ext_vector_type(4)));
typedef __bf16 bf16x8 __attribute__((ext_vector_type(8)));

__device__ __forceinline__ void split_bf16(const float* x, bf16x8& hi, bf16x8& lo)
{
    #pragma unroll
    for (int i = 0; i < 8; ++i) {
        float v = x[i];
        __bf16 h = (__bf16)v;
        hi[i] = h;
        lo[i] = (__bf16)(v - (float)h);
    }
}

// ---------------------------------------------------------------------------
// MFMA GEMM (BNK-true): C[1024x1024] = A @ B^T * scale + bias
// ---------------------------------------------------------------------------
__global__ __launch_bounds__(256)
void mfma_gemm_bt(const float* __restrict__ A, const float* __restrict__ Bm,
                  const float* __restrict__ bias, float* __restrict__ C, float scale)
{
    const int m0 = blockIdx.x * 64;
    const int n0 = blockIdx.y * 64;
    const int w   = threadIdx.x >> 6;
    const int l   = threadIdx.x & 63;
    const int row = l & 15;
    const int kg  = l >> 4;

    const float* ap = A + (size_t)(m0 + w * 16 + row) * H + kg * 8;
    const float* bp = Bm + (size_t)(n0 + row) * H + kg * 8;

    f32x4 acc[4] = {};
    for (int k0 = 0; k0 < H; k0 += 32) {
        float a8[8];
        *reinterpret_cast<float4*>(&a8[0]) = *reinterpret_cast<const float4*>(ap + k0);
        *reinterpret_cast<float4*>(&a8[4]) = *reinterpret_cast<const float4*>(ap + k0 + 4);
        bf16x8 ahi, alo;
        split_bf16(a8, ahi, alo);
        #pragma unroll
        for (int j = 0; j < 4; ++j) {
            float b8[8];
            const float* bjp = bp + (size_t)j * 16 * H + k0;
            *reinterpret_cast<float4*>(&b8[0]) = *reinterpret_cast<const float4*>(bjp);
            *reinterpret_cast<float4*>(&b8[4]) = *reinterpret_cast<const float4*>(bjp + 4);
            bf16x8 bhi, blo;
            split_bf16(b8, bhi, blo);
            acc[j] = __builtin_amdgcn_mfma_f32_16x16x32_bf16(ahi, bhi, acc[j], 0, 0, 0);
            acc[j] = __builtin_amdgcn_mfma_f32_16x16x32_bf16(ahi, blo, acc[j], 0, 0, 0);
            acc[j] = __builtin_amdgcn_mfma_f32_16x16x32_bf16(alo, bhi, acc[j], 0, 0, 0);
        }
    }
    #pragma unroll
    for (int j = 0; j < 4; ++j) {
        int n = n0 + j * 16 + row;
        float bb = bias ? bias[n] : 0.f;
        #pragma unroll
        for (int r = 0; r < 4; ++r) {
            int m = m0 + w * 16 + kg * 4 + r;
            C[(size_t)m * H + n] = acc[j][r] * scale + bb;
        }
    }
}

// ---------------------------------------------------------------------------
// N-proj MFMA: N = (q @ Wk) * scale -> pre-split bf16 hi/lo [m][n]
// ---------------------------------------------------------------------------
__global__ __launch_bounds__(256)
void ngemm_mfma(const float* __restrict__ q, const float* __restrict__ Wk,
                __bf16* __restrict__ Nhi, __bf16* __restrict__ Nlo, float scale)
{
    const int m0 = blockIdx.x * 64;
    const int n0 = blockIdx.y * 64;
    const int w   = threadIdx.x >> 6;
    const int l   = threadIdx.x & 63;
    const int row = l & 15;
    const int kg  = l >> 4;

    const float* ap = q + (size_t)(m0 + w * 16 + row) * H + kg * 8;
    const float* bp = Wk + (size_t)(kg * 8) * H + n0 + row;

    f32x4 acc[4] = {};
    for (int k0 = 0; k0 < H; k0 += 32) {
        float a8[8];
        *reinterpret_cast<float4*>(&a8[0]) = *reinterpret_cast<const float4*>(ap + k0);
        *reinterpret_cast<float4*>(&a8[4]) = *reinterpret_cast<const float4*>(ap + k0 + 4);
        bf16x8 ahi, alo;
        split_bf16(a8, ahi, alo);
        #pragma unroll
        for (int j = 0; j < 4; ++j) {
            float b8[8];
            #pragma unroll
            for (int e = 0; e < 8; ++e)
                b8[e] = bp[(size_t)(k0 + e) * H + j * 16];
            bf16x8 bhi, blo;
            split_bf16(b8, bhi, blo);
            acc[j] = __builtin_amdgcn_mfma_f32_16x16x32_bf16(ahi, bhi, acc[j], 0, 0, 0);
            acc[j] = __builtin_amdgcn_mfma_f32_16x16x32_bf16(ahi, blo, acc[j], 0, 0, 0);
            acc[j] = __builtin_amdgcn_mfma_f32_16x16x32_bf16(alo, bhi, acc[j], 0, 0, 0);
        }
    }
    #pragma unroll
    for (int j = 0; j < 4; ++j) {
        int n = n0 + j * 16 + row;
        #pragma unroll
        for (int r = 0; r < 4; ++r) {
            int m = m0 + w * 16 + kg * 4 + r;
            float v = acc[j][r] * scale;
            __bf16 hi = (__bf16)v;
            Nhi[(size_t)m * H + n] = hi;
            Nlo[(size_t)m * H + n] = (__bf16)(v - (float)hi);
        }
    }
}

// ---------------------------------------------------------------------------
// c[b,qi] = scale * dot(q[b,qi,:], bk)
// ---------------------------------------------------------------------------
__global__ __launch_bounds__(256)
void cvec_kernel(const float* __restrict__ q, const float* __restrict__ bk,
                 float* __restrict__ cvec, float scale)
{
    int r = blockIdx.x * 4 + (threadIdx.x >> 6);
    int l = threadIdx.x & 63;
    float s = 0.f;
    #pragma unroll
    for (int i = 0; i < 16; ++i)
        s += q[(size_t)r * H + l + 64 * i] * bk[l + 64 * i];
    #pragma unroll
    for (int off = 32; off; off >>= 1)
        s += __shfl_down(s, off);
    if (l == 0) cvec[r] = s * scale;
}

// ---------------------------------------------------------------------------
// scores[b,s,qi] = sum_h keys[b,s,h]*N[b,qi,h] + c[b,qi]
// XCD-swizzled blocks (xcd x owns b in {2x,2x+1}); N LDS-staged per 128-k
// chunk; keys chunk register-prefetched.
// ---------------------------------------------------------------------------
__global__ __launch_bounds__(256)
void scores_mfma(const float* __restrict__ keys,
                 const __bf16* __restrict__ Nhi, const __bf16* __restrict__ Nlo,
                 const float* __restrict__ cvec, float* __restrict__ scores)
{
    // bijective swizzle over 1024 blocks: xcd = id & 7 (round-robin HW map)
    const int id = blockIdx.x;
    const int x  = id & 7;
    const int m  = id >> 3;              // 0..127
    const int b  = 2 * x + (m >> 6);     // 2 batches per XCD
    const int s0 = (m & 63) * 64;

    const int t   = threadIdx.x;
    const int w   = t >> 6;
    const int l   = t & 63;
    const int row = l & 15;
    const int kg  = l >> 4;

    __shared__ __bf16 nshH[64][16][8];   // [qi][kb][e], 128-k chunk (16 KB)
    __shared__ __bf16 nshL[64][16][8];

    const float* ka = keys + ((size_t)b * SEQ + s0 + w * 16 + row) * H + kg * 8;
    const __bf16* nhb = Nhi + (size_t)b * BQ * H;
    const __bf16* nlb = Nlo + (size_t)b * BQ * H;

    // staging decomposition: thread t covers (qi = rep*16 + t>>4, kb = t&15)
    const int sqi = t >> 4;
    const int skb = t & 15;

    f32x4 acc[4] = {};
    for (int kc = 0; kc < H; kc += 128) {
        // 1) prefetch keys chunk into regs (independent of LDS)
        float4 kr[8];
        #pragma unroll
        for (int ii = 0; ii < 4; ++ii) {
            kr[2 * ii + 0] = *reinterpret_cast<const float4*>(ka + kc + ii * 32);
            kr[2 * ii + 1] = *reinterpret_cast<const float4*>(ka + kc + ii * 32 + 4);
        }
        // 2) load N chunk into regs
        bf16x8 nh[4], nl[4];
        #pragma unroll
        for (int rep = 0; rep < 4; ++rep) {
            size_t goff = (size_t)(rep * 16 + sqi) * H + kc + skb * 8;
            nh[rep] = *reinterpret_cast<const bf16x8*>(nhb + goff);
            nl[rep] = *reinterpret_cast<const bf16x8*>(nlb + goff);
        }
        // 3) wait until previous chunk's readers are done, then write LDS
        __syncthreads();
        #pragma unroll
        for (int rep = 0; rep < 4; ++rep) {
            *reinterpret_cast<bf16x8*>(&nshH[rep * 16 + sqi][skb][0]) = nh[rep];
            *reinterpret_cast<bf16x8*>(&nshL[rep * 16 + sqi][skb][0]) = nl[rep];
        }
        __syncthreads();
        // 4) compute 4 k-iters from regs + LDS
        #pragma unroll
        for (int ii = 0; ii < 4; ++ii) {
            float a8[8];
            *reinterpret_cast<float4*>(&a8[0]) = kr[2 * ii + 0];
            *reinterpret_cast<float4*>(&a8[4]) = kr[2 * ii + 1];
            bf16x8 ahi, alo;
            split_bf16(a8, ahi, alo);
            const int kb = ii * 4 + kg;
            #pragma unroll
            for (int j = 0; j < 4; ++j) {
                bf16x8 bhi = *reinterpret_cast<const bf16x8*>(&nshH[j * 16 + row][kb][0]);
                bf16x8 blo = *reinterpret_cast<const bf16x8*>(&nshL[j * 16 + row][kb][0]);
                acc[j] = __builtin_amdgcn_mfma_f32_16x16x32_bf16(ahi, bhi, acc[j], 0, 0, 0);
                acc[j] = __builtin_amdgcn_mfma_f32_16x16x32_bf16(ahi, blo, acc[j], 0, 0, 0);
                acc[j] = __builtin_amdgcn_mfma_f32_16x16x32_bf16(alo, bhi, acc[j], 0, 0, 0);
            }
        }
    }
    #pragma unroll
    for (int j = 0; j < 4; ++j) {
        int qi = j * 16 + row;
        float c = cvec[b * BQ + qi];
        #pragma unroll
        for (int r = 0; r < 4; ++r) {
            int s = s0 + w * 16 + kg * 4 + r;
            scores[((size_t)b * SEQ + s) * BQ + qi] = acc[j][r] + c;
        }
    }
}

// ---------------------------------------------------------------------------
// softmax over s — partial stats
// ---------------------------------------------------------------------------
__global__ __launch_bounds__(256)
void sm_partial(const float* __restrict__ scores, float* __restrict__ pmax,
                float* __restrict__ psum)
{
    const int b  = blockIdx.y;
    const int ch = blockIdx.x;
    const int t  = threadIdx.x;
    const int qi = t & 63;
    const int g  = t >> 6;
    const float* sb = scores + ((size_t)b * SEQ + ch * 128) * BQ;
    float v[32];
    #pragma unroll
    for (int i = 0; i < 32; ++i)
        v[i] = sb[(size_t)(g + i * 4) * BQ + qi];
    float m = v[0];
    #pragma unroll
    for (int i = 1; i < 32; ++i) m = fmaxf(m, v[i]);
    __shared__ float red[4][64];
    red[g][qi] = m;
    __syncthreads();
    float M = fmaxf(fmaxf(red[0][qi], red[1][qi]), fmaxf(red[2][qi], red[3][qi]));
    float sum = 0.f;
    #pragma unroll
    for (int i = 0; i < 32; ++i) sum += __expf(v[i] - M);
    __syncthreads();
    red[g][qi] = sum;
    __syncthreads();
    if (g == 0) {
        float ssum = red[0][qi] + red[1][qi] + red[2][qi] + red[3][qi];
        pmax[((size_t)b * 32 + ch) * 64 + qi] = M;
        psum[((size_t)b * 32 + ch) * 64 + qi] = ssum;
    }
}

__global__ void sm_combine(const float* __restrict__ pmax,
                           const float* __restrict__ psum,
                           float* __restrict__ gstat)
{
    int b  = blockIdx.x;
    int qi = threadIdx.x; // 64
    float m = -1e30f;
    for (int c = 0; c < 32; ++c)
        m = fmaxf(m, pmax[((size_t)b * 32 + c) * 64 + qi]);
    float s = 0.f;
    for (int c = 0; c < 32; ++c)
        s += psum[((size_t)b * 32 + c) * 64 + qi] *
             __expf(pmax[((size_t)b * 32 + c) * 64 + qi] - m);
    gstat[(size_t)b * 64 + qi] = m;
    gstat[(size_t)(NB + b) * 64 + qi] = 1.f / s;
}

// normalize in place (f32, d_out) + write bf16 TRANSPOSED copy abfT[b][qi][s]
__global__ __launch_bounds__(256)
void sm_norm(float* __restrict__ attn, const float* __restrict__ gstat,
             __hip_bfloat16* __restrict__ abfT)
{
    __shared__ float tile[64][133];
    const int b  = blockIdx.y;
    const int ch = blockIdx.x;
    const int t  = threadIdx.x;
    const int qi = t & 63;
    const int g  = t >> 6;
    const float M   = gstat[(size_t)b * 64 + qi];
    const float inv = gstat[(size_t)(NB + b) * 64 + qi];
    float* sb = attn + ((size_t)b * SEQ + ch * 128) * BQ;
    #pragma unroll 8
    for (int i = 0; i < 32; ++i) {
        int sl = g + i * 4;
        size_t idx = (size_t)sl * BQ + qi;
        float w = __expf(sb[idx] - M) * inv;
        sb[idx] = w;
        tile[qi][sl] = w;
    }
    __syncthreads();
    const int qo = t >> 2;
    const int c  = (t & 3) * 32;
    __hip_bfloat16* dst = abfT + ((size_t)(b * BQ + qo)) * SEQ + ch * 128 + c;
    #pragma unroll
    for (int v = 0; v < 4; ++v) {
        bf16x8 w8;
        #pragma unroll
        for (int e = 0; e < 8; ++e)
            w8[e] = (__bf16)tile[qo][c + v * 8 + e];
        *reinterpret_cast<bf16x8*>(dst + v * 8) = w8;
    }
}

// ---------------------------------------------------------------------------
// Tpart[sc][b][qi][h] = sum_{s in chunk} abfT[b,qi,s] * values[b,s,h]
// ---------------------------------------------------------------------------
__global__ __launch_bounds__(256)
void tmat_mfma(const __hip_bfloat16* __restrict__ abfT,
               const float* __restrict__ values,
               float* __restrict__ Tpart, int schunk)
{
    const int b   = blockIdx.z;
    const int sc  = blockIdx.y;
    const int h0  = blockIdx.x * 128;
    const int w   = threadIdx.x >> 6;
    const int l   = threadIdx.x & 63;
    const int row = l & 15;
    const int kg  = l >> 4;
    const int sbase = sc * schunk;

    const __hip_bfloat16* ap = abfT + ((size_t)b * BQ + row) * SEQ + sbase + kg * 8;
    const float* vp = values + ((size_t)b * SEQ + sbase + kg * 8) * H + h0 + w * 32 + row;

    f32x4 acc[4][2] = {};
    for (int k0 = 0; k0 < schunk; k0 += 32) {
        bf16x8 a[4];
        #pragma unroll
        for (int i = 0; i < 4; ++i)
            a[i] = *reinterpret_cast<const bf16x8*>(ap + (size_t)i * 16 * SEQ + k0);
        #pragma unroll
        for (int j = 0; j < 2; ++j) {
            float b8[8];
            const float* bp = vp + (size_t)k0 * H + j * 16;
            #pragma unroll
            for (int e = 0; e < 8; ++e) b8[e] = bp[(size_t)e * H];
            bf16x8 bhi, blo;
            split_bf16(b8, bhi, blo);
            #pragma unroll
            for (int i = 0; i < 4; ++i) {
                acc[i][j] = __builtin_amdgcn_mfma_f32_16x16x32_bf16(a[i], bhi, acc[i][j], 0, 0, 0);
                acc[i][j] = __builtin_amdgcn_mfma_f32_16x16x32_bf16(a[i], blo, acc[i][j], 0, 0, 0);
            }
        }
    }
    float* tp = Tpart + ((size_t)sc * NB + b) * BQ * H;
    #pragma unroll
    for (int i = 0; i < 4; ++i) {
        #pragma unroll
        for (int j = 0; j < 2; ++j) {
            int h = h0 + w * 32 + j * 16 + row;
            #pragma unroll
            for (int r = 0; r < 4; ++r) {
                int qi = i * 16 + kg * 4 + r;
                tp[(size_t)qi * H + h] = acc[i][j][r];
            }
        }
    }
}

// ---------------------------------------------------------------------------
// In-place partial reduction: Tpart[0][i] = sum_p Tpart[p][i]
// ---------------------------------------------------------------------------
template<int SC>
__global__ __launch_bounds__(256)
void tsum_kernel(float* __restrict__ Tpart)
{
    const size_t stride = (size_t)NB * BQ * H;
    size_t i = ((size_t)blockIdx.x * 256 + threadIdx.x) * 4;
    f32x4 s = *reinterpret_cast<const f32x4*>(Tpart + i);
    #pragma unroll
    for (int p = 1; p < SC; ++p)
        s += *reinterpret_cast<const f32x4*>(Tpart + p * stride + i);
    *reinterpret_cast<f32x4*>(Tpart + i) = s;
}

// ---------------------------------------------------------------------------
extern "C" void kernel_launch(void* const* d_in, const int* in_sizes, int n_in,
                              void* d_out, int out_size, void* d_ws, size_t ws_size,
                              hipStream_t stream)
{
    const float* queries = (const float*)d_in[0];
    const float* keys    = (const float*)d_in[1];
    const float* values  = (const float*)d_in[2];
    const float* Wq = (const float*)d_in[3];
    const float* bq = (const float*)d_in[4];
    const float* Wk = (const float*)d_in[5];
    const float* bk = (const float*)d_in[6];
    const float* Wv = (const float*)d_in[7];
    const float* bv = (const float*)d_in[8];

    float* out     = (float*)d_out;
    float* context = out;                          // 16*64*1024 f32
    float* attn    = out + (size_t)NB * BQ * H;    // 16*4096*64 f32

    const int SC = (ws_size >= (41ull << 20)) ? 8 : 2;
    const int schunk = SEQ / SC;

    char* ws = (char*)d_ws;
    float* q     = (float*)ws;                              // 4 MB  [0,4)
    __bf16* Nhi  = (__bf16*)(ws + (4ull << 20));            // 2 MB  [4,6)
    __bf16* Nlo  = (__bf16*)(ws + (6ull << 20));            // 2 MB  [6,8)
    float* Tpart = (float*)ws;                              // SC*4 MB (overlaps q/N, dead by then)
    __hip_bfloat16* abfT = (__hip_bfloat16*)(ws + (size_t)SC * (4ull << 20)); // 8 MB
    char* smalls = ws + (size_t)SC * (4ull << 20) + (8ull << 20);
    float* cvec  = (float*)smalls;                          // 4 KB
    float* gstat = (float*)(smalls + (64u << 10));          // 8 KB
    float* pmax  = (float*)(smalls + (128u << 10));         // 128 KB
    float* psum  = (float*)(smalls + (256u << 10));         // 128 KB

    const float scale = 0.03125f; // 1/sqrt(1024)

    // q = queries @ Wq^T + bq   (MFMA hi/lo)
    mfma_gemm_bt<<<dim3(16, 16), 256, 0, stream>>>(queries, Wq, bq, q, 1.0f);
    // N = (q @ Wk) * scale  -> pre-split bf16 hi/lo
    ngemm_mfma<<<dim3(16, 16), 256, 0, stream>>>(q, Wk, Nhi, Nlo, scale);
    // c = (q . bk) * scale
    cvec_kernel<<<256, 256, 0, stream>>>(q, bk, cvec, scale);
    // scores -> attn region of d_out (1D grid, XCD-swizzled inside)
    scores_mfma<<<1024, 256, 0, stream>>>(keys, Nhi, Nlo, cvec, attn);
    // softmax over s
    sm_partial<<<dim3(32, NB), 256, 0, stream>>>(attn, pmax, psum);
    sm_combine<<<NB, 64, 0, stream>>>(pmax, psum, gstat);
    sm_norm<<<dim3(32, NB), 256, 0, stream>>>(attn, gstat, abfT);
    // T partials = attn^T @ values (MFMA, split-S)
    tmat_mfma<<<dim3(H / 128, SC, NB), 256, 0, stream>>>(abfT, values, Tpart, schunk);
    // Tsum (in place into partial 0)
    if (SC == 8) tsum_kernel<8><<<1024, 256, 0, stream>>>(Tpart);
    else         tsum_kernel<2><<<1024, 256, 0, stream>>>(Tpart);
    // context = Tsum @ Wv^T + bv  (MFMA hi/lo)
    mfma_gemm_bt<<<dim3(16, 16), 256, 0, stream>>>(Tpart, Wv, bv, context, 1.0f);
}